// Round 1
// baseline (2828.398 us; speedup 1.0000x reference)
//
#include <hip/hip_runtime.h>
#include <hip/hip_bf16.h>

#define NOER 100000
#define NCON 20000
#define NCLS 1000
#define FENT 64
#define HID 128
#define ESR 200000
#define EEP 400000
#define ECOV 400000
#define EBEL 100000
#define NEG 0.2f

__device__ __forceinline__ void atomAdd(float* p, float v) { unsafeAtomicAdd(p, v); }

// h[n,c] = sum_k e[n,k]*W[k,c] + b[c]; one block (128 thr) per node, F_ENT=64 input
__global__ void k_linproj(const float* __restrict__ e, const float* __restrict__ W,
                          const float* __restrict__ b, float* __restrict__ h) {
    __shared__ float xs[FENT];
    int n = blockIdx.x, c = threadIdx.x;
    if (c < FENT) xs[c] = e[(size_t)n * FENT + c];
    __syncthreads();
    float acc = b[c];
#pragma unroll
    for (int k = 0; k < FENT; ++k) acc = fmaf(xs[k], W[k * HID + c], acc);
    h[(size_t)n * HID + c] = acc;
}

// hs = x @ W (128x128), sl[n] = hs[n] . a_s ; one block (128 thr) per node
__global__ void k_src(const float* __restrict__ x, const float* __restrict__ W,
                      const float* __restrict__ as_, float* __restrict__ hs,
                      float* __restrict__ sl) {
    __shared__ float xs[HID];
    __shared__ float red[HID];
    int n = blockIdx.x, c = threadIdx.x;
    xs[c] = x[(size_t)n * HID + c];
    __syncthreads();
    float acc = 0.f;
#pragma unroll
    for (int k = 0; k < HID; ++k) acc = fmaf(xs[k], W[k * HID + c], acc);
    hs[(size_t)n * HID + c] = acc;
    red[c] = acc * as_[c];
    __syncthreads();
#pragma unroll
    for (int s = 64; s > 0; s >>= 1) {
        if (c < s) red[c] += red[c + s];
        __syncthreads();
    }
    if (c == 0) sl[n] = red[0];
}

// wv[k] = sum_c Wd[k,c]*ad[c]   (dst transform collapses to mat-vec)
__global__ void k_wdvec(const float* __restrict__ Wd, const float* __restrict__ ad,
                        float* __restrict__ wv) {
    int r = threadIdx.x;
    float acc = 0.f;
    for (int c = 0; c < HID; ++c) acc = fmaf(Wd[r * HID + c], ad[c], acc);
    wv[r] = acc;
}

// dl[n] = x[n,:] . wv   (one 64-lane wave per node)
__global__ void k_dlogit(const float* __restrict__ x, const float* __restrict__ wv,
                         float* __restrict__ dl, int nd) {
    int t = blockIdx.x * blockDim.x + threadIdx.x;
    int n = t >> 6, lane = t & 63;
    if (n >= nd) return;
    float p = x[(size_t)n * HID + lane] * wv[lane] +
              x[(size_t)n * HID + 64 + lane] * wv[64 + lane];
#pragma unroll
    for (int off = 32; off; off >>= 1) p += __shfl_down(p, off);
    if (lane == 0) dl[n] = p;
}

// per edge: ex = exp(leaky_relu(sl[src]+dl[dst])); denom[dst] += ex
__global__ void k_edge_ex(const int* __restrict__ src, const int* __restrict__ dst,
                          int ne, int nloop,
                          const float* __restrict__ sl, const float* __restrict__ dl,
                          float* __restrict__ ex, float* __restrict__ denom) {
    int e = blockIdx.x * blockDim.x + threadIdx.x;
    if (e >= ne + nloop) return;
    int s, d;
    if (e < ne) { s = src[e]; d = dst[e]; } else { s = e - ne; d = s; }
    float lg = sl[s] + dl[d];
    lg = lg > 0.f ? lg : NEG * lg;
    float v = expf(lg);
    ex[e] = v;
    atomAdd(denom + d, v);
}

// per (edge, channel): acc[dst,c] += (ex/denom[dst]) * hs[src,c]; 2 edges per 256-thr block
__global__ void k_scatter(const int* __restrict__ src, const int* __restrict__ dst,
                          int ne, int nloop,
                          const float* __restrict__ ex, const float* __restrict__ denom,
                          const float* __restrict__ hs, float* __restrict__ acc) {
    int e = blockIdx.x * 2 + (threadIdx.x >> 7);
    int c = threadIdx.x & (HID - 1);
    if (e >= ne + nloop) return;
    int s, d;
    if (e < ne) { s = src[e]; d = dst[e]; } else { s = e - ne; d = s; }
    float a = ex[e] / denom[d];
    atomAdd(acc + (size_t)d * HID + c, a * hs[(size_t)s * HID + c]);
}

// h = 0.5*(acc + bA + bB)  (HeteroConv mean of 2 relations, bias folded in)
__global__ void k_merge2(const float* __restrict__ acc, const float* __restrict__ bA,
                         const float* __restrict__ bB, float* __restrict__ h, int n) {
    int i = blockIdx.x * blockDim.x + threadIdx.x;
    if (i >= n) return;
    int c = i & (HID - 1);
    h[i] = 0.5f * (acc[i] + bA[c] + bB[c]);
}

__global__ void k_merge1(const float* __restrict__ acc, const float* __restrict__ b,
                         float* __restrict__ h, int n) {
    int i = blockIdx.x * blockDim.x + threadIdx.x;
    if (i >= n) return;
    h[i] = acc[i] + b[i & (HID - 1)];
}

// s1[n] = [x_oer|h_oer][n] . Wc[0:192]; s2[n] = . Wc[192:384]  (one wave per node)
__global__ void k_score(const float* __restrict__ x, const float* __restrict__ h,
                        const float* __restrict__ Wc, float* __restrict__ s1,
                        float* __restrict__ s2, int n_nodes) {
    int t = blockIdx.x * blockDim.x + threadIdx.x;
    int n = t >> 6, lane = t & 63;
    if (n >= n_nodes) return;
    float xv = x[(size_t)n * FENT + lane];
    float h0 = h[(size_t)n * HID + lane], h1 = h[(size_t)n * HID + 64 + lane];
    float p1 = xv * Wc[lane] + h0 * Wc[64 + lane] + h1 * Wc[128 + lane];
    float p2 = xv * Wc[192 + lane] + h0 * Wc[256 + lane] + h1 * Wc[320 + lane];
#pragma unroll
    for (int off = 32; off; off >>= 1) { p1 += __shfl_down(p1, off); p2 += __shfl_down(p2, off); }
    if (lane == 0) { s1[n] = p1; s2[n] = p2; }
}

__global__ void k_final(const int* __restrict__ src, const int* __restrict__ dst,
                        const float* __restrict__ s1, const float* __restrict__ s2,
                        const float* __restrict__ bcls, float* __restrict__ out) {
    int e = blockIdx.x * blockDim.x + threadIdx.x;
    if (e >= ESR) return;
    out[e] = s1[src[e]] + s2[dst[e]] + bcls[0];
}

extern "C" void kernel_launch(void* const* d_in, const int* in_sizes, int n_in,
                              void* d_out, int out_size, void* d_ws, size_t ws_size,
                              hipStream_t stream) {
    const float* x_oer   = (const float*)d_in[0];
    const float* e_oer   = (const float*)d_in[3];
    const float* e_con   = (const float*)d_in[4];
    const float* e_cls   = (const float*)d_in[5];
    const float* W_lin   = (const float*)d_in[6];
    const float* b_lin   = (const float*)d_in[7];
    const float* Wsrc    = (const float*)d_in[8];
    const float* Wdst    = (const float*)d_in[9];
    const float* att_src = (const float*)d_in[10];
    const float* att_dst = (const float*)d_in[11];
    const float* b_gat   = (const float*)d_in[12];
    const float* W_cls   = (const float*)d_in[13];
    const float* b_cls   = (const float*)d_in[14];
    const int* ei_sr   = (const int*)d_in[15];
    const int* ei_cov  = (const int*)d_in[16];
    const int* ei_bel  = (const int*)d_in[17];
    const int* ei_rcov = (const int*)d_in[18];
    const int* ei_rbel = (const int*)d_in[19];
    const int* ei_ep   = (const int*)d_in[20];

    float* ws = (float*)d_ws;
    size_t o = 0;
    float* h_oer   = ws + o; o += (size_t)NOER * HID;
    float* h_con   = ws + o; o += (size_t)NCON * HID;
    float* h_cls   = ws + o; o += (size_t)NCLS * HID;
    float* acc_oer = ws + o; o += (size_t)NOER * HID;
    float* acc_con = ws + o; o += (size_t)NCON * HID;
    float* acc_cls = ws + o; o += (size_t)NCLS * HID;
    float* hs      = ws + o; o += (size_t)NOER * HID;
    float* sl      = ws + o; o += NOER;
    float* dl      = ws + o; o += NOER;
    float* ex      = ws + o; o += (EEP + NOER);
    float* denom   = ws + o; o += NOER;
    float* wv      = ws + o; o += HID;
    float* s1      = ws + o; o += NOER;
    float* s2      = ws + o; o += NOER;

    // input projections: h = e @ W_lin[t] + b_lin[t]
    k_linproj<<<NOER, HID, 0, stream>>>(e_oer, W_lin + 0 * FENT * HID, b_lin + 0 * HID, h_oer);
    k_linproj<<<NCON, HID, 0, stream>>>(e_con, W_lin + 1 * FENT * HID, b_lin + 1 * HID, h_con);
    k_linproj<<<NCLS, HID, 0, stream>>>(e_cls, W_lin + 2 * FENT * HID, b_lin + 2 * HID, h_cls);

    auto rel = [&](int l, int r, const float* xsrc, int ns, const float* xdst, int nd,
                   const int* esrc, const int* edst, int ne, int nloop, float* accb) {
        int idx = l * 5 + r;
        k_src<<<ns, HID, 0, stream>>>(xsrc, Wsrc + (size_t)idx * HID * HID, att_src + idx * HID, hs, sl);
        k_wdvec<<<1, HID, 0, stream>>>(Wdst + (size_t)idx * HID * HID, att_dst + idx * HID, wv);
        k_dlogit<<<(nd * 64 + 255) / 256, 256, 0, stream>>>(xdst, wv, dl, nd);
        hipMemsetAsync(denom, 0, nd * sizeof(float), stream);
        int tot = ne + nloop;
        k_edge_ex<<<(tot + 255) / 256, 256, 0, stream>>>(esrc, edst, ne, nloop, sl, dl, ex, denom);
        k_scatter<<<(tot + 1) / 2, 256, 0, stream>>>(esrc, edst, ne, nloop, ex, denom, hs, accb);
    };

    for (int l = 0; l < 2; ++l) {
        hipMemsetAsync(acc_oer, 0, ((size_t)NOER + NCON + NCLS) * HID * sizeof(float), stream);
        rel(l, 0, h_oer, NOER, h_oer, NOER, ei_ep, ei_ep + EEP, EEP, NOER, acc_oer);
        rel(l, 1, h_oer, NOER, h_con, NCON, ei_cov, ei_cov + ECOV, ECOV, 0, acc_con);
        rel(l, 2, h_con, NCON, h_cls, NCLS, ei_bel, ei_bel + EBEL, EBEL, 0, acc_cls);
        rel(l, 3, h_con, NCON, h_oer, NOER, ei_rcov, ei_rcov + ECOV, ECOV, 0, acc_oer);
        rel(l, 4, h_cls, NCLS, h_con, NCON, ei_rbel, ei_rbel + EBEL, EBEL, 0, acc_con);
        int idx = l * 5;
        k_merge2<<<(NOER * HID + 255) / 256, 256, 0, stream>>>(acc_oer, b_gat + (idx + 0) * HID,
                                                               b_gat + (idx + 3) * HID, h_oer, NOER * HID);
        k_merge2<<<(NCON * HID + 255) / 256, 256, 0, stream>>>(acc_con, b_gat + (idx + 1) * HID,
                                                               b_gat + (idx + 4) * HID, h_con, NCON * HID);
        k_merge1<<<(NCLS * HID + 255) / 256, 256, 0, stream>>>(acc_cls, b_gat + (idx + 2) * HID,
                                                               h_cls, NCLS * HID);
    }

    k_score<<<(NOER * 64 + 255) / 256, 256, 0, stream>>>(x_oer, h_oer, W_cls, s1, s2, NOER);
    k_final<<<(ESR + 255) / 256, 256, 0, stream>>>(ei_sr, ei_sr + ESR, s1, s2, b_cls, (float*)d_out);
}